// Round 13
// baseline (186.457 us; speedup 1.0000x reference)
//
#include <hip/hip_runtime.h>
#include <hip/hip_bf16.h>

#define EF 128
#define KNN 8

typedef __attribute__((ext_vector_type(8)))  short          short8;
typedef __attribute__((ext_vector_type(8)))  unsigned short ushort8;
typedef __attribute__((ext_vector_type(4)))  float          f32x4;
typedef __attribute__((ext_vector_type(16))) float          f32x16;

// software round-to-nearest-even f32 -> bf16 bits (cold paths)
static __device__ __forceinline__ unsigned short f2bf(float f) {
    unsigned int x = __float_as_uint(f);
    unsigned int r = x + 0x7fffu + ((x >> 16) & 1u);
    return (unsigned short)(r >> 16);
}
// sanctioned compiler conversion (RNE) for hot paths
static __device__ __forceinline__ short f2bf_hw(float f) {
    return (short)__bfloat16_as_ushort(__float2bfloat16(f));
}

// ---------------------------------------------------------------------------
// pack_kernel:
//   W1[:128] -> W1p, 32x32x16 B-frag order (zgemm):
//     s = (((kt*4+nt)*64+l)*8+j); k = kt*16+(l>>5)*8+j; n = nt*32+(l&31)
//   W2      -> W2p, 16x16x32 B-frag order (edge kernel):
//     s = (((kt*8+nt)*64+l)*8+j); k = kt*32+(l>>4)*8+j; n = nt*16+(l&15)
// ---------------------------------------------------------------------------
__global__ __launch_bounds__(256) void pack_kernel(
    const float* __restrict__ W1, const float* __restrict__ W2,
    unsigned short* __restrict__ W1p, unsigned short* __restrict__ W2p)
{
    int t = blockIdx.x * 256 + threadIdx.x;
    if (t < 16384) {
        int s = t;
        int j  = s & 7;
        int l  = (s >> 3) & 63;
        int nt = (s >> 9) & 3;
        int kt = (s >> 11) & 7;
        int k = kt * 16 + (l >> 5) * 8 + j;
        int n = nt * 32 + (l & 31);
        W1p[s] = f2bf(W1[k * EF + n]);
    } else if (t < 32768) {
        int s = t - 16384;
        int j  = s & 7;
        int l  = (s >> 3) & 63;
        int nt = (s >> 9) & 7;
        int kt = (s >> 12) & 3;
        int k = kt * 32 + (l >> 4) * 8 + j;
        int n = nt * 16 + (l & 15);
        W2p[s] = f2bf(W2[k * EF + n]);
    }
}

// ---------------------------------------------------------------------------
// zgemm_kernel: Z[p][d] = bf16( b1[d] + sum_k input[p][k] * W1[k][d] )
// (unchanged 32x32x16 structure, verified rounds 2/5/7/8/9/11/12)
// ---------------------------------------------------------------------------
__global__ __launch_bounds__(256) void zgemm_kernel(
    const float* __restrict__ input,
    const unsigned short* __restrict__ W1p,
    const float* __restrict__ b1,
    unsigned short* __restrict__ Z,
    int npts, int ntiles)
{
    int l = threadIdx.x & 63;
    int tile = blockIdx.x * 4 + (threadIdx.x >> 6);
    if (tile >= ntiles) return;
    int p0   = tile * 32;
    int r    = l & 31;
    int half = l >> 5;
    int prow = p0 + r;
    if (prow >= npts) prow = npts - 1;      // clamp for ragged tail (reads only)
    const float* Arow = input + (size_t)prow * EF;

    f32x16 acc[4];
#pragma unroll
    for (int nt = 0; nt < 4; ++nt)
#pragma unroll
        for (int i = 0; i < 16; ++i) acc[nt][i] = 0.f;

#pragma unroll
    for (int kt = 0; kt < 8; ++kt) {
        int k0 = kt * 16 + half * 8;
        float4 a0 = *(const float4*)(Arow + k0);
        float4 a1 = *(const float4*)(Arow + k0 + 4);
        short8 a;
        a[0] = f2bf_hw(a0.x); a[1] = f2bf_hw(a0.y);
        a[2] = f2bf_hw(a0.z); a[3] = f2bf_hw(a0.w);
        a[4] = f2bf_hw(a1.x); a[5] = f2bf_hw(a1.y);
        a[6] = f2bf_hw(a1.z); a[7] = f2bf_hw(a1.w);
#pragma unroll
        for (int nt = 0; nt < 4; ++nt) {
            short8 b = *(const short8*)(W1p + ((size_t)((kt * 4 + nt) * 64 + l)) * 8);
            acc[nt] = __builtin_amdgcn_mfma_f32_32x32x16_bf16(a, b, acc[nt], 0, 0, 0);
        }
    }

    int col = l & 31;
#pragma unroll
    for (int nt = 0; nt < 4; ++nt) {
        float bb = b1[nt * 32 + col];
#pragma unroll
        for (int reg = 0; reg < 16; ++reg) {
            int row = (reg & 3) + 8 * (reg >> 2) + 4 * half;
            int p = p0 + row;
            if (p < npts)
                Z[(size_t)p * EF + nt * 32 + col] = f2bf(acc[nt][reg] + bb);
        }
    }
}

// ---------------------------------------------------------------------------
// edge_mfma_kernel (16x16x32): PERSISTENT blocks. Round-9 per-tile body
// (proven 74 us) wrapped in a grid-stride loop; straight-line code, named
// register buffers only (no lambdas / runtime-indexed arrays -> no scratch).
// W2 staged to LDS once per block lifetime (1024 blocks, not 6250).
// ---------------------------------------------------------------------------
__global__ __launch_bounds__(512) void edge_mfma_kernel(
    const unsigned short* __restrict__ Z,
    const int* __restrict__ knn_idx,
    const float* __restrict__ knn_xyz,
    const unsigned short* __restrict__ W2p,
    const float* __restrict__ W1,       // xyz rows at +128*EF (f32)
    const float* __restrict__ b2,
    float* __restrict__ out,
    int npts, int nedges, int ntiles)
{
    __shared__ short8 w2lds[2048];      // 32 KB: full packed W2, frag order
    __shared__ float  wlds[3 * EF];     // W1 rows 128..130, f32

    // ---- stage W2 fragments + xyz weights into LDS (once per block) -------
    {
        const short8* W2v = (const short8*)W2p;
#pragma unroll
        for (int i = threadIdx.x; i < 2048; i += 512)
            w2lds[i] = W2v[i];
        for (int t = threadIdx.x; t < 3 * EF; t += 512)
            wlds[t] = W1[EF * EF + t];
    }
    __syncthreads();

    int l  = threadIdx.x & 63;
    int r  = l & 15;                    // edge row within tile
    int hi = l >> 4;                    // k-group 0..3
    int wid    = blockIdx.x * 8 + (threadIdx.x >> 6);
    int stride = gridDim.x * 8;

    for (int tile = wid; tile < ntiles; tile += stride) {
        // ---- fetch (straight-line, named registers) -----------------------
        int edge = tile * 16 + r;
        if (edge >= nedges) edge = nedges - 1;   // clamp (reads only)
        int   idx = knn_idx[edge];
        float x = knn_xyz[edge * 3 + 0];
        float y = knn_xyz[edge * 3 + 1];
        float z = knn_xyz[edge * 3 + 2];
        const unsigned short* Zrow = Z + (size_t)idx * EF;
        ushort8 zv0 = *(const ushort8*)(Zrow + 0 * 32 + hi * 8);
        ushort8 zv1 = *(const ushort8*)(Zrow + 1 * 32 + hi * 8);
        ushort8 zv2 = *(const ushort8*)(Zrow + 2 * 32 + hi * 8);
        ushort8 zv3 = *(const ushort8*)(Zrow + 3 * 32 + hi * 8);

        // ---- compute ------------------------------------------------------
        f32x4 acc[8];
#pragma unroll
        for (int nt = 0; nt < 8; ++nt)
#pragma unroll
            for (int i = 0; i < 4; ++i) acc[nt][i] = 0.f;

#pragma unroll
        for (int kt = 0; kt < 4; ++kt) {
            ushort8 zv = (kt == 0) ? zv0 : (kt == 1) ? zv1 : (kt == 2) ? zv2 : zv3;
            int d0 = kt * 32 + hi * 8;
            float4 wx0 = *(const float4*)&wlds[0 * EF + d0];
            float4 wx1 = *(const float4*)&wlds[0 * EF + d0 + 4];
            float4 wy0 = *(const float4*)&wlds[1 * EF + d0];
            float4 wy1 = *(const float4*)&wlds[1 * EF + d0 + 4];
            float4 wz0 = *(const float4*)&wlds[2 * EF + d0];
            float4 wz1 = *(const float4*)&wlds[2 * EF + d0 + 4];
            float wxa[8] = {wx0.x, wx0.y, wx0.z, wx0.w, wx1.x, wx1.y, wx1.z, wx1.w};
            float wya[8] = {wy0.x, wy0.y, wy0.z, wy0.w, wy1.x, wy1.y, wy1.z, wy1.w};
            float wza[8] = {wz0.x, wz0.y, wz0.z, wz0.w, wz1.x, wz1.y, wz1.z, wz1.w};

            short8 a;
#pragma unroll
            for (int j = 0; j < 8; ++j) {
                float h = __uint_as_float(((unsigned int)zv[j]) << 16); // bf16->f32
                h = fmaf(x, wxa[j], h);
                h = fmaf(y, wya[j], h);
                h = fmaf(z, wza[j], h);
                h = fmaxf(h, 0.01f * h);    // leaky_relu, exact both signs
                a[j] = f2bf_hw(h);
            }
#pragma unroll
            for (int nt = 0; nt < 8; ++nt) {
                short8 b = w2lds[(kt * 8 + nt) * 64 + l];   // ds_read_b128
                acc[nt] = __builtin_amdgcn_mfma_f32_16x16x32_bf16(a, b, acc[nt], 0, 0, 0);
            }
        }

        // ---- max-pool epilogue -------------------------------------------
        int col = l & 15;
#pragma unroll
        for (int nt = 0; nt < 8; ++nt) {
            float m = fmaxf(fmaxf(acc[nt][0], acc[nt][1]),
                            fmaxf(acc[nt][2], acc[nt][3]));
            m = fmaxf(m, __shfl_xor(m, 16));     // combine group pairs
            if (!(hi & 1)) {
                int p = tile * 2 + (hi >> 1);
                if (p < npts)
                    out[(size_t)p * EF + nt * 16 + col] = m + b2[nt * 16 + col];
            }
        }
    }
}

extern "C" void kernel_launch(void* const* d_in, const int* in_sizes, int n_in,
                              void* d_out, int out_size, void* d_ws, size_t ws_size,
                              hipStream_t stream) {
    const float* input   = (const float*)d_in[0];
    const int*   knn_idx = (const int*)  d_in[1];
    const float* knn_xyz = (const float*)d_in[2];
    const float* W1      = (const float*)d_in[3];
    const float* b1      = (const float*)d_in[4];
    const float* W2      = (const float*)d_in[5];
    const float* b2      = (const float*)d_in[6];
    float*       out     = (float*)d_out;

    int npts   = in_sizes[0] / EF;          // 100000
    int nedges = in_sizes[1];               // npts * 8

    // workspace layout
    unsigned short* W1p = (unsigned short*)d_ws;                  // 16384
    unsigned short* W2p = W1p + 16384;                            // 16384
    unsigned short* Z   = (unsigned short*)((char*)d_ws + 65536); // npts*128

    pack_kernel<<<128, 256, 0, stream>>>(W1, W2, W1p, W2p);

    int ztiles = (npts + 31) / 32;
    zgemm_kernel<<<(ztiles + 3) / 4, 256, 0, stream>>>(
        input, W1p, b1, Z, npts, ztiles);

    int etiles = (nedges + 15) / 16;
    int eblocks = (etiles + 7) / 8;
    if (eblocks > 1024) eblocks = 1024;     // persistent: 4 blocks/CU x 256 CU
    edge_mfma_kernel<<<eblocks, 512, 0, stream>>>(
        Z, knn_idx, knn_xyz, W2p, W1, b2, out, npts, nedges, etiles);
}

// Round 14
// 99.827 us; speedup vs baseline: 1.8678x; 1.8678x over previous
//
#include <hip/hip_runtime.h>
#include <hip/hip_bf16.h>

#define EF 128
#define KNN 8

typedef __attribute__((ext_vector_type(8)))  short          short8;
typedef __attribute__((ext_vector_type(8)))  unsigned short ushort8;
typedef __attribute__((ext_vector_type(16))) float          f32x16;

// software round-to-nearest-even f32 -> bf16 bits (cold paths)
static __device__ __forceinline__ unsigned short f2bf(float f) {
    unsigned int x = __float_as_uint(f);
    unsigned int r = x + 0x7fffu + ((x >> 16) & 1u);
    return (unsigned short)(r >> 16);
}
// sanctioned compiler conversion (RNE) for hot paths
static __device__ __forceinline__ short f2bf_hw(float f) {
    return (short)__bfloat16_as_ushort(__float2bfloat16(f));
}

// ---------------------------------------------------------------------------
// pack_kernel: BOTH W1[:128] and W2 -> 32x32x16 B-frag order:
//   s = (((kt*4+nt)*64+l)*8+j); k = kt*16+(l>>5)*8+j; n = nt*32+(l&31)
// (same verified order as rounds 2-13 for W1p; W2p now reuses it)
// ---------------------------------------------------------------------------
__global__ __launch_bounds__(256) void pack_kernel(
    const float* __restrict__ W1, const float* __restrict__ W2,
    unsigned short* __restrict__ W1p, unsigned short* __restrict__ W2p)
{
    int t = blockIdx.x * 256 + threadIdx.x;
    if (t < 2 * 16384) {
        int m = t >> 14;            // 0: W1, 1: W2
        int s = t & 16383;
        int j  = s & 7;
        int l  = (s >> 3) & 63;
        int nt = (s >> 9) & 3;
        int kt = (s >> 11) & 7;
        int k = kt * 16 + (l >> 5) * 8 + j;
        int n = nt * 32 + (l & 31);
        const float* W = m ? W2 : W1;
        unsigned short* P = m ? W2p : W1p;
        P[s] = f2bf(W[k * EF + n]);
    }
}

// ---------------------------------------------------------------------------
// zgemm_kernel: Z[p][d] = bf16( b1[d] + sum_k input[p][k] * W1[k][d] )
// (unchanged 32x32x16 structure, verified rounds 2-13)
// ---------------------------------------------------------------------------
__global__ __launch_bounds__(256) void zgemm_kernel(
    const float* __restrict__ input,
    const unsigned short* __restrict__ W1p,
    const float* __restrict__ b1,
    unsigned short* __restrict__ Z,
    int npts, int ntiles)
{
    int l = threadIdx.x & 63;
    int tile = blockIdx.x * 4 + (threadIdx.x >> 6);
    if (tile >= ntiles) return;
    int p0   = tile * 32;
    int r    = l & 31;
    int half = l >> 5;
    int prow = p0 + r;
    if (prow >= npts) prow = npts - 1;      // clamp for ragged tail (reads only)
    const float* Arow = input + (size_t)prow * EF;

    f32x16 acc[4];
#pragma unroll
    for (int nt = 0; nt < 4; ++nt)
#pragma unroll
        for (int i = 0; i < 16; ++i) acc[nt][i] = 0.f;

#pragma unroll
    for (int kt = 0; kt < 8; ++kt) {
        int k0 = kt * 16 + half * 8;
        float4 a0 = *(const float4*)(Arow + k0);
        float4 a1 = *(const float4*)(Arow + k0 + 4);
        short8 a;
        a[0] = f2bf_hw(a0.x); a[1] = f2bf_hw(a0.y);
        a[2] = f2bf_hw(a0.z); a[3] = f2bf_hw(a0.w);
        a[4] = f2bf_hw(a1.x); a[5] = f2bf_hw(a1.y);
        a[6] = f2bf_hw(a1.z); a[7] = f2bf_hw(a1.w);
#pragma unroll
        for (int nt = 0; nt < 4; ++nt) {
            short8 b = *(const short8*)(W1p + ((size_t)((kt * 4 + nt) * 64 + l)) * 8);
            acc[nt] = __builtin_amdgcn_mfma_f32_32x32x16_bf16(a, b, acc[nt], 0, 0, 0);
        }
    }

    int col = l & 31;
#pragma unroll
    for (int nt = 0; nt < 4; ++nt) {
        float bb = b1[nt * 32 + col];
#pragma unroll
        for (int reg = 0; reg < 16; ++reg) {
            int row = (reg & 3) + 8 * (reg >> 2) + 4 * half;
            int p = p0 + row;
            if (p < npts)
                Z[(size_t)p * EF + nt * 32 + col] = f2bf(acc[nt][reg] + bb);
        }
    }
}

// ---------------------------------------------------------------------------
// edge_mfma_kernel (32x32x16): per wave a 32-edge tile (= 4 points).
// Halves W2 ds_read and MFMA instruction counts per edge vs the 16x16x32
// version (same FLOPs/bytes). Non-persistent; one tile per wave.
// A-frag: row = l&31 (edge), k = kt*16 + (l>>5)*8 + j.
// C/D:    col = l&31, row = (reg&3) + 8*(reg>>2) + 4*(l>>5)  [verified].
// ---------------------------------------------------------------------------
__global__ __launch_bounds__(512) void edge_mfma_kernel(
    const unsigned short* __restrict__ Z,
    const int* __restrict__ knn_idx,
    const float* __restrict__ knn_xyz,
    const unsigned short* __restrict__ W2p,
    const float* __restrict__ W1,       // xyz rows at +128*EF (f32)
    const float* __restrict__ b2,
    float* __restrict__ out,
    int npts, int nedges, int ntiles)
{
    __shared__ short8 w2lds[2048];      // 32 KB: full packed W2, frag order
    __shared__ float  wlds[3 * EF];     // W1 rows 128..130, f32

    int l    = threadIdx.x & 63;
    int r    = l & 31;                  // edge row within tile
    int half = l >> 5;
    int tile = blockIdx.x * 8 + (threadIdx.x >> 6);
    bool active = tile < ntiles;

    // ---- issue scattered gathers FIRST (latency hides under staging) ------
    int edge = active ? (tile * 32 + r) : 0;
    if (edge >= nedges) edge = nedges - 1;   // clamp (reads only)
    int   idx = knn_idx[edge];
    float x = knn_xyz[edge * 3 + 0];
    float y = knn_xyz[edge * 3 + 1];
    float z = knn_xyz[edge * 3 + 2];
    const unsigned short* Zrow = Z + (size_t)idx * EF;
    ushort8 zv[8];
#pragma unroll
    for (int kt = 0; kt < 8; ++kt)
        zv[kt] = *(const ushort8*)(Zrow + kt * 16 + half * 8);

    // ---- stage W2 fragments + xyz weights into LDS ------------------------
    {
        const short8* W2v = (const short8*)W2p;
#pragma unroll
        for (int i = threadIdx.x; i < 2048; i += 512)
            w2lds[i] = W2v[i];
        for (int t = threadIdx.x; t < 3 * EF; t += 512)
            wlds[t] = W1[EF * EF + t];
    }
    __syncthreads();
    if (!active) return;

    f32x16 acc[4];
#pragma unroll
    for (int nt = 0; nt < 4; ++nt)
#pragma unroll
        for (int i = 0; i < 16; ++i) acc[nt][i] = 0.f;

#pragma unroll
    for (int kt = 0; kt < 8; ++kt) {
        int d0 = kt * 16 + half * 8;
        float4 wx0 = *(const float4*)&wlds[0 * EF + d0];
        float4 wx1 = *(const float4*)&wlds[0 * EF + d0 + 4];
        float4 wy0 = *(const float4*)&wlds[1 * EF + d0];
        float4 wy1 = *(const float4*)&wlds[1 * EF + d0 + 4];
        float4 wz0 = *(const float4*)&wlds[2 * EF + d0];
        float4 wz1 = *(const float4*)&wlds[2 * EF + d0 + 4];
        float wxa[8] = {wx0.x, wx0.y, wx0.z, wx0.w, wx1.x, wx1.y, wx1.z, wx1.w};
        float wya[8] = {wy0.x, wy0.y, wy0.z, wy0.w, wy1.x, wy1.y, wy1.z, wy1.w};
        float wza[8] = {wz0.x, wz0.y, wz0.z, wz0.w, wz1.x, wz1.y, wz1.z, wz1.w};

        short8 a;
#pragma unroll
        for (int j = 0; j < 8; ++j) {
            float h = __uint_as_float(((unsigned int)zv[kt][j]) << 16); // bf16->f32
            h = fmaf(x, wxa[j], h);
            h = fmaf(y, wya[j], h);
            h = fmaf(z, wza[j], h);
            h = fmaxf(h, 0.01f * h);    // leaky_relu, exact both signs
            a[j] = f2bf_hw(h);
        }
#pragma unroll
        for (int nt = 0; nt < 4; ++nt) {
            short8 b = w2lds[(kt * 4 + nt) * 64 + l];   // ONE ds_read per MFMA
            acc[nt] = __builtin_amdgcn_mfma_f32_32x32x16_bf16(a, b, acc[nt], 0, 0, 0);
        }
    }

    // ---- max-pool epilogue: point q = rows 8q..8q+7 = regs 4q..4q+3 x halves
    int col = l & 31;
    int p0  = tile * 4;
#pragma unroll
    for (int nt = 0; nt < 4; ++nt) {
        float bb = b2[nt * 32 + col];
#pragma unroll
        for (int q = 0; q < 4; ++q) {
            float m = fmaxf(fmaxf(acc[nt][4 * q + 0], acc[nt][4 * q + 1]),
                            fmaxf(acc[nt][4 * q + 2], acc[nt][4 * q + 3]));
            m = fmaxf(m, __shfl_xor(m, 32));     // combine the two halves
            int p = p0 + q;
            if (half == 0 && p < npts)
                out[(size_t)p * EF + nt * 32 + col] = m + bb;
        }
    }
}

extern "C" void kernel_launch(void* const* d_in, const int* in_sizes, int n_in,
                              void* d_out, int out_size, void* d_ws, size_t ws_size,
                              hipStream_t stream) {
    const float* input   = (const float*)d_in[0];
    const int*   knn_idx = (const int*)  d_in[1];
    const float* knn_xyz = (const float*)d_in[2];
    const float* W1      = (const float*)d_in[3];
    const float* b1      = (const float*)d_in[4];
    const float* W2      = (const float*)d_in[5];
    const float* b2      = (const float*)d_in[6];
    float*       out     = (float*)d_out;

    int npts   = in_sizes[0] / EF;          // 100000
    int nedges = in_sizes[1];               // npts * 8

    // workspace layout
    unsigned short* W1p = (unsigned short*)d_ws;                  // 16384
    unsigned short* W2p = W1p + 16384;                            // 16384
    unsigned short* Z   = (unsigned short*)((char*)d_ws + 65536); // npts*128

    pack_kernel<<<128, 256, 0, stream>>>(W1, W2, W1p, W2p);

    int ztiles = (npts + 31) / 32;
    zgemm_kernel<<<(ztiles + 3) / 4, 256, 0, stream>>>(
        input, W1p, b1, Z, npts, ztiles);

    int etiles = (nedges + 31) / 32;        // 32 edges per wave
    int eblocks = (etiles + 7) / 8;         // 8 waves per block
    edge_mfma_kernel<<<eblocks, 512, 0, stream>>>(
        Z, knn_idx, knn_xyz, W2p, W1, b2, out, npts, nedges, etiles);
}

// Round 15
// 95.190 us; speedup vs baseline: 1.9588x; 1.0487x over previous
//
#include <hip/hip_runtime.h>
#include <hip/hip_bf16.h>

#define EF 128
#define KNN 8

typedef __attribute__((ext_vector_type(8)))  _Float16       h16x8;
typedef __attribute__((ext_vector_type(16))) float          f32x16;

// ---------------------------------------------------------------------------
// pack_kernel: BOTH W1[:128] and W2 -> 32x32x16 B-frag order, f16:
//   s = (((kt*4+nt)*64+l)*8+j); k = kt*16+(l>>5)*8+j; n = nt*32+(l&31)
// ---------------------------------------------------------------------------
__global__ __launch_bounds__(256) void pack_kernel(
    const float* __restrict__ W1, const float* __restrict__ W2,
    _Float16* __restrict__ W1p, _Float16* __restrict__ W2p)
{
    int t = blockIdx.x * 256 + threadIdx.x;
    if (t < 2 * 16384) {
        int m = t >> 14;            // 0: W1, 1: W2
        int s = t & 16383;
        int j  = s & 7;
        int l  = (s >> 3) & 63;
        int nt = (s >> 9) & 3;
        int kt = (s >> 11) & 7;
        int k = kt * 16 + (l >> 5) * 8 + j;
        int n = nt * 32 + (l & 31);
        const float* W = m ? W2 : W1;
        _Float16* P = m ? W2p : W1p;
        P[s] = (_Float16)W[k * EF + n];
    }
}

// ---------------------------------------------------------------------------
// zgemm_kernel: Z[p][d] = f16( b1[d] + sum_k input[p][k] * W1[k][d] )
// (verified 32x32x16 structure, now f16 operands)
// ---------------------------------------------------------------------------
__global__ __launch_bounds__(256) void zgemm_kernel(
    const float* __restrict__ input,
    const _Float16* __restrict__ W1p,
    const float* __restrict__ b1,
    _Float16* __restrict__ Z,
    int npts, int ntiles)
{
    int l = threadIdx.x & 63;
    int tile = blockIdx.x * 4 + (threadIdx.x >> 6);
    if (tile >= ntiles) return;
    int p0   = tile * 32;
    int r    = l & 31;
    int half = l >> 5;
    int prow = p0 + r;
    if (prow >= npts) prow = npts - 1;      // clamp for ragged tail (reads only)
    const float* Arow = input + (size_t)prow * EF;

    f32x16 acc[4];
#pragma unroll
    for (int nt = 0; nt < 4; ++nt)
#pragma unroll
        for (int i = 0; i < 16; ++i) acc[nt][i] = 0.f;

#pragma unroll
    for (int kt = 0; kt < 8; ++kt) {
        int k0 = kt * 16 + half * 8;
        float4 a0 = *(const float4*)(Arow + k0);
        float4 a1 = *(const float4*)(Arow + k0 + 4);
        h16x8 a;
        a[0] = (_Float16)a0.x; a[1] = (_Float16)a0.y;
        a[2] = (_Float16)a0.z; a[3] = (_Float16)a0.w;
        a[4] = (_Float16)a1.x; a[5] = (_Float16)a1.y;
        a[6] = (_Float16)a1.z; a[7] = (_Float16)a1.w;
#pragma unroll
        for (int nt = 0; nt < 4; ++nt) {
            h16x8 b = *(const h16x8*)(W1p + ((size_t)((kt * 4 + nt) * 64 + l)) * 8);
            acc[nt] = __builtin_amdgcn_mfma_f32_32x32x16_f16(a, b, acc[nt], 0, 0, 0);
        }
    }

    int col = l & 31;
#pragma unroll
    for (int nt = 0; nt < 4; ++nt) {
        float bb = b1[nt * 32 + col];
#pragma unroll
        for (int reg = 0; reg < 16; ++reg) {
            int row = (reg & 3) + 8 * (reg >> 2) + 4 * half;
            int p = p0 + row;
            if (p < npts)
                Z[(size_t)p * EF + nt * 32 + col] = (_Float16)(acc[nt][reg] + bb);
        }
    }
}

// ---------------------------------------------------------------------------
// edge_mfma_kernel (32x32x16, f16): per wave a 32-edge tile (= 4 points).
// A-build in PACKED f16: 3x v_pk_fma_f16 + pk_mul/pk_max per 2 elements,
// zero conversions (gathered Z is already f16, result regs ARE the A-frag).
// ---------------------------------------------------------------------------
__global__ __launch_bounds__(512) void edge_mfma_kernel(
    const _Float16* __restrict__ Z,
    const int* __restrict__ knn_idx,
    const float* __restrict__ knn_xyz,
    const _Float16* __restrict__ W2p,
    const float* __restrict__ W1,       // xyz rows at +128*EF (f32)
    const float* __restrict__ b2,
    float* __restrict__ out,
    int npts, int nedges, int ntiles)
{
    __shared__ h16x8    w2lds[2048];    // 32 KB: full packed W2, frag order
    __shared__ _Float16 wlds[3 * EF];   // W1 rows 128..130, f16

    int l    = threadIdx.x & 63;
    int r    = l & 31;                  // edge row within tile
    int half = l >> 5;
    int tile = blockIdx.x * 8 + (threadIdx.x >> 6);
    bool active = tile < ntiles;

    // ---- issue scattered gathers FIRST (latency hides under staging) ------
    int edge = active ? (tile * 32 + r) : 0;
    if (edge >= nedges) edge = nedges - 1;   // clamp (reads only)
    int   idx = knn_idx[edge];
    float x = knn_xyz[edge * 3 + 0];
    float y = knn_xyz[edge * 3 + 1];
    float z = knn_xyz[edge * 3 + 2];
    const _Float16* Zrow = Z + (size_t)idx * EF;
    h16x8 g0 = *(const h16x8*)(Zrow + 0 * 16 + half * 8);
    h16x8 g1 = *(const h16x8*)(Zrow + 1 * 16 + half * 8);
    h16x8 g2 = *(const h16x8*)(Zrow + 2 * 16 + half * 8);
    h16x8 g3 = *(const h16x8*)(Zrow + 3 * 16 + half * 8);
    h16x8 g4 = *(const h16x8*)(Zrow + 4 * 16 + half * 8);
    h16x8 g5 = *(const h16x8*)(Zrow + 5 * 16 + half * 8);
    h16x8 g6 = *(const h16x8*)(Zrow + 6 * 16 + half * 8);
    h16x8 g7 = *(const h16x8*)(Zrow + 7 * 16 + half * 8);

    // ---- stage W2 fragments + xyz weights (f16) into LDS ------------------
    {
        const h16x8* W2v = (const h16x8*)W2p;
#pragma unroll
        for (int i = threadIdx.x; i < 2048; i += 512)
            w2lds[i] = W2v[i];
        for (int t = threadIdx.x; t < 3 * EF; t += 512)
            wlds[t] = (_Float16)W1[EF * EF + t];
    }
    __syncthreads();
    if (!active) return;

    // splat scalars to packed f16
    _Float16 xh = (_Float16)x, yh = (_Float16)y, zh = (_Float16)z;
    h16x8 xs = {xh, xh, xh, xh, xh, xh, xh, xh};
    h16x8 ys = {yh, yh, yh, yh, yh, yh, yh, yh};
    h16x8 zs = {zh, zh, zh, zh, zh, zh, zh, zh};
    const _Float16 c001 = (_Float16)0.01f;
    h16x8 cs = {c001, c001, c001, c001, c001, c001, c001, c001};

    f32x16 acc[4];
#pragma unroll
    for (int nt = 0; nt < 4; ++nt)
#pragma unroll
        for (int i = 0; i < 16; ++i) acc[nt][i] = 0.f;

#pragma unroll
    for (int kt = 0; kt < 8; ++kt) {
        h16x8 g = (kt == 0) ? g0 : (kt == 1) ? g1 : (kt == 2) ? g2 : (kt == 3) ? g3
                : (kt == 4) ? g4 : (kt == 5) ? g5 : (kt == 6) ? g6 : g7;
        int d0 = kt * 16 + half * 8;
        h16x8 wx = *(const h16x8*)&wlds[0 * EF + d0];
        h16x8 wy = *(const h16x8*)&wlds[1 * EF + d0];
        h16x8 wz = *(const h16x8*)&wlds[2 * EF + d0];

        h16x8 h = __builtin_elementwise_fma(xs, wx, g);
        h = __builtin_elementwise_fma(ys, wy, h);
        h = __builtin_elementwise_fma(zs, wz, h);
        h = __builtin_elementwise_max(h, h * cs);   // leaky_relu, exact both signs

#pragma unroll
        for (int nt = 0; nt < 4; ++nt) {
            h16x8 b = w2lds[(kt * 4 + nt) * 64 + l];   // ds_read_b128
            acc[nt] = __builtin_amdgcn_mfma_f32_32x32x16_f16(h, b, acc[nt], 0, 0, 0);
        }
    }

    // ---- max-pool epilogue: point q = rows 8q..8q+7 = regs 4q..4q+3 x halves
    int col = l & 31;
    int p0  = tile * 4;
#pragma unroll
    for (int nt = 0; nt < 4; ++nt) {
        float bb = b2[nt * 32 + col];
#pragma unroll
        for (int q = 0; q < 4; ++q) {
            float m = fmaxf(fmaxf(acc[nt][4 * q + 0], acc[nt][4 * q + 1]),
                            fmaxf(acc[nt][4 * q + 2], acc[nt][4 * q + 3]));
            m = fmaxf(m, __shfl_xor(m, 32));     // combine the two halves
            int p = p0 + q;
            if (half == 0 && p < npts)
                out[(size_t)p * EF + nt * 32 + col] = m + bb;
        }
    }
}

extern "C" void kernel_launch(void* const* d_in, const int* in_sizes, int n_in,
                              void* d_out, int out_size, void* d_ws, size_t ws_size,
                              hipStream_t stream) {
    const float* input   = (const float*)d_in[0];
    const int*   knn_idx = (const int*)  d_in[1];
    const float* knn_xyz = (const float*)d_in[2];
    const float* W1      = (const float*)d_in[3];
    const float* b1      = (const float*)d_in[4];
    const float* W2      = (const float*)d_in[5];
    const float* b2      = (const float*)d_in[6];
    float*       out     = (float*)d_out;

    int npts   = in_sizes[0] / EF;          // 100000
    int nedges = in_sizes[1];               // npts * 8

    // workspace layout
    _Float16* W1p = (_Float16*)d_ws;                   // 16384
    _Float16* W2p = W1p + 16384;                       // 16384
    _Float16* Z   = (_Float16*)((char*)d_ws + 65536);  // npts*128

    pack_kernel<<<128, 256, 0, stream>>>(W1, W2, W1p, W2p);

    int ztiles = (npts + 31) / 32;
    zgemm_kernel<<<(ztiles + 3) / 4, 256, 0, stream>>>(
        input, W1p, b1, Z, npts, ztiles);

    int etiles = (nedges + 31) / 32;        // 32 edges per wave
    int eblocks = (etiles + 7) / 8;         // 8 waves per block
    edge_mfma_kernel<<<eblocks, 512, 0, stream>>>(
        Z, knn_idx, knn_xyz, W2p, W1, b2, out, npts, nedges, etiles);
}